// Round 8
// baseline (248.730 us; speedup 1.0000x reference)
//
#include <hip/hip_runtime.h>

#define KE_CONST 14.3996454784255f

#define P2_SHIFT 15
#define P2_CHUNK 32768            // 128 KB LDS accumulator per chunk (scan phase)
#define MAXC     4
#define MAXE     16               // pair table up to 256 entries (4 KB LDS)
#define ELEM_CAP 131072           // 128 KB LDS elem table cap
#define DN_THR   1024
#define DN_BLOCKS 256
#define SCAN_THR 1024
#define SCAN_B   256              // balanced scan blocks (1/CU)
#define CNT_B    256              // count blocks in prep (MUST match DN_BLOCKS slicing)
#define EB       32               // elem-argmax blocks in prep

// ---------------- deterministic proportional block allocation for the scan ----------
__device__ __forceinline__ void scan_alloc(const unsigned* __restrict__ g_,
        int& nb0, int& nb1, int& nb2, int& nb3,
        int& st1, int& st2, int& st3,
        long long& g0, long long& g1, long long& g2, long long& g3) {
    g0 = g_[0]; g1 = g_[1]; g2 = g_[2]; g3 = g_[3];
    long long tot = g0 + g1 + g2 + g3; if (tot < 1) tot = 1;
    nb0 = (int)((g0 * SCAN_B) / tot); if (nb0 < 1) nb0 = 1;
    nb1 = (int)((g1 * SCAN_B) / tot); if (nb1 < 1) nb1 = 1;
    nb2 = (int)((g2 * SCAN_B) / tot); if (nb2 < 1) nb2 = 1;
    nb3 = (int)((g3 * SCAN_B) / tot); if (nb3 < 1) nb3 = 1;
    int sum = nb0 + nb1 + nb2 + nb3;
    while (sum > SCAN_B) {
        if      (nb0 >= nb1 && nb0 >= nb2 && nb0 >= nb3) nb0--;
        else if (nb1 >= nb2 && nb1 >= nb3)               nb1--;
        else if (nb2 >= nb3)                             nb2--;
        else                                             nb3--;
        sum--;
    }
    while (sum < SCAN_B) {
        if      (nb0 >= nb1 && nb0 >= nb2 && nb0 >= nb3) nb0++;
        else if (nb1 >= nb2 && nb1 >= nb3)               nb1++;
        else if (nb2 >= nb3)                             nb2++;
        else                                             nb3++;
        sum++;
    }
    st1 = nb0; st2 = nb0 + nb1; st3 = nb0 + nb1 + nb2;
}

// ---------------- per-edge bf16 value from pair-table entry ----------------
__device__ __forceinline__ unsigned enc_val16(float xv, const float4& p) {
    float t = xv * p.x;
    float phi = 0.1818f  * __expf(-3.2f    * t)
              + 0.5099f  * __expf(-0.9423f * t)
              + 0.2802f  * __expf(-0.4028f * t)
              + 0.02817f * __expf(-0.2016f * t);
    float rr = xv * p.w;
    float r2 = rr * rr;
    float r6 = r2 * r2 * r2;
    float env = 1.0f - 28.0f * r6 + 48.0f * r6 * rr - 21.0f * r6 * r2;
    float val = fmaxf(p.y * phi / xv * env, 0.0f);     // clamp r->1 cancellation negatives
    unsigned e = (__float_as_uint(val) + 0x8000u) >> 16;   // round-to-nearest bf16
    return (xv < p.z) ? e : 0u;
}

// ---------------- wave-aggregated bucketed scatter (<=4 LDS atomics / wave-round) ----
__device__ __forceinline__ void scatter_bal(unsigned rw, float xv, const float4& p,
                                            unsigned* cur, const unsigned* seg,
                                            unsigned* __restrict__ packedB, int lane) {
    unsigned cc = rw >> P2_SHIFT;
    unsigned w  = ((rw & (P2_CHUNK - 1)) << 16) | enc_val16(xv, p);
    unsigned long long m0 = __ballot(cc == 0), m1 = __ballot(cc == 1),
                       m2 = __ballot(cc == 2), m3 = __ballot(cc == 3);
    unsigned long long mine = (cc == 0) ? m0 : (cc == 1) ? m1 : (cc == 2) ? m2 : m3;
    int ldr = __ffsll((long long)mine) - 1;
    unsigned base = 0;
    if (lane == ldr) base = atomicAdd(&cur[cc], (unsigned)__popcll(mine));
    base = __shfl(base, ldr, 64);
    unsigned pos = base + (unsigned)__popcll(mine & ((1ull << lane) - 1ull));
    packedB[(size_t)seg[cc] + pos] = w;
}

// zero-mask: ~30% of words encode bf16 0 (env cutoff) — skip the DS RMW entirely.
#define ACC1(W) { if ((W) & 0xFFFFu) \
    atomicAdd(&acc[(W) >> 16], __uint_as_float(((W) & 0xFFFFu) << 16)); }
#define ACC4(Q) { ACC1((Q).x); ACC1((Q).y); ACC1((Q).z); ACC1((Q).w); }

// ---------------- in-LDS per-chunk inclusive prefix over 256 block histograms -------
#define PREFIX_HIST(sb, h_lds, t)                                              \
    {                                                                          \
        const int c_ = (t) >> 8, bb_ = (t) & 255;                              \
        (sb)[t] = (h_lds)[bb_ * MAXC + c_];                                    \
        __syncthreads();                                                       \
        for (int off_ = 1; off_ < DN_BLOCKS; off_ <<= 1) {                     \
            unsigned add_ = (bb_ >= off_) ? (sb)[c_ * DN_BLOCKS + bb_ - off_]  \
                                          : 0u;                                \
            __syncthreads();                                                   \
            (sb)[t] += add_;                                                   \
            __syncthreads();                                                   \
        }                                                                      \
    }

// ---------------- dispatch 1: count hist (0..255), argmax + out-zero, pairs ----------
__global__ __launch_bounds__(1024)
void zbl_prep(const float* __restrict__ node_attrs,
              const int* __restrict__ ei,
              const int* __restrict__ atomic_numbers,
              const float* __restrict__ covalent_radii,
              unsigned char* __restrict__ elem_g,
              float4* __restrict__ pair_tab,
              unsigned* __restrict__ hist,
              float* __restrict__ out,
              int n_edges, int n_elem, int n_nodes) {
    const int b = blockIdx.x, t = threadIdx.x, lane = t & 63;

    if (b < CNT_B) {
        __shared__ unsigned h[MAXC];
        if (t < MAXC) h[t] = 0u;
        __syncthreads();
        long long e0 = (((long long)b * n_edges) / CNT_B) & ~3LL;
        long long e1 = (b == CNT_B - 1) ? (long long)n_edges
                     : ((((long long)(b + 1) * n_edges) / CNT_B) & ~3LL);
        const int* r = ei + n_edges;
        unsigned c0 = 0, c1 = 0, c2 = 0, c3 = 0;
        long long vend = e1 & ~3LL;
        for (long long p = e0 + (long long)t * 4; p + 4 <= vend; p += 1024LL * 4) {
            int4 a = *(const int4*)(r + p);
            unsigned cc;
            cc = ((unsigned)a.x) >> P2_SHIFT; c0 += (cc==0); c1 += (cc==1); c2 += (cc==2); c3 += (cc==3);
            cc = ((unsigned)a.y) >> P2_SHIFT; c0 += (cc==0); c1 += (cc==1); c2 += (cc==2); c3 += (cc==3);
            cc = ((unsigned)a.z) >> P2_SHIFT; c0 += (cc==0); c1 += (cc==1); c2 += (cc==2); c3 += (cc==3);
            cc = ((unsigned)a.w) >> P2_SHIFT; c0 += (cc==0); c1 += (cc==1); c2 += (cc==2); c3 += (cc==3);
        }
        for (long long e2 = vend + t; e2 < e1; e2 += 1024) {
            unsigned cc = ((unsigned)r[e2]) >> P2_SHIFT;
            c0 += (cc==0); c1 += (cc==1); c2 += (cc==2); c3 += (cc==3);
        }
        for (int o = 32; o; o >>= 1) {
            c0 += __shfl_down(c0, o, 64); c1 += __shfl_down(c1, o, 64);
            c2 += __shfl_down(c2, o, 64); c3 += __shfl_down(c3, o, 64);
        }
        if (lane == 0) {
            atomicAdd(&h[0], c0); atomicAdd(&h[1], c1);
            atomicAdd(&h[2], c2); atomicAdd(&h[3], c3);
        }
        __syncthreads();
        if (t < MAXC) hist[b * MAXC + t] = h[t];   // plain store — no gcount, no memset
    } else if (b < CNT_B + EB) {
        int bb = b - CNT_B;
        int n0 = (int)(((long long)bb * n_nodes) / EB);
        int n1 = (int)(((long long)(bb + 1) * n_nodes) / EB);
        for (int n = n0 + t; n < n1; n += 1024) {
            const float* row = node_attrs + (size_t)n * n_elem;
            float best = row[0]; int bi = 0;
            for (int i = 1; i < n_elem; ++i) {
                float v = row[i];
                if (v > best) { best = v; bi = i; }
            }
            elem_g[n] = (unsigned char)bi;
            out[n] = 0.0f;                       // scan flushes atomically into out
        }
    } else {
        int np = n_elem * n_elem;
        if (t < np) {
            int eu = t / n_elem, ev = t - eu * n_elem;
            int Zu = atomic_numbers[eu], Zv = atomic_numbers[ev];
            float zu = (float)Zu, zv = (float)Zv;
            float inv_a = (__powf(zu, 0.3f) + __powf(zv, 0.3f)) * (1.0f / (0.4543f * 0.529f));
            float rmax  = covalent_radii[Zu] + covalent_radii[Zv];
            pair_tab[t] = make_float4(inv_a, 0.5f * KE_CONST * zu * zv, rmax, 1.0f / rmax);
        }
    }
}

// ---------------- dispatch 2: prefix-from-hist + dense compute + GLOBAL-bucket scatter
__global__ __launch_bounds__(DN_THR)
void zbl_dense(const float* __restrict__ x,
               const int* __restrict__ ei,
               const unsigned char* __restrict__ elem_g,
               const float4* __restrict__ pair_tab,
               const unsigned* __restrict__ hist,
               unsigned* __restrict__ packedB,
               int n_edges, int n_elem, int n_nodes) {
    __shared__ __align__(16) unsigned char elem[ELEM_CAP];
    __shared__ float4 pt[MAXE * MAXE];
    __shared__ unsigned h_lds[DN_BLOCKS * MAXC];
    __shared__ unsigned sb[MAXC * DN_BLOCKS];
    __shared__ unsigned cur[MAXC], seg[MAXC];

    const int b = blockIdx.x, t = threadIdx.x, lane = t & 63;

    for (int i = t; i < DN_BLOCKS * MAXC; i += DN_THR) h_lds[i] = hist[i];
    __syncthreads();
    PREFIX_HIST(sb, h_lds, t);

    if (t == 0) {
        unsigned tot0 = sb[0 * DN_BLOCKS + 255];
        unsigned tot1 = sb[1 * DN_BLOCKS + 255];
        unsigned tot2 = sb[2 * DN_BLOCKS + 255];
        // global base of bucket c + this block's exclusive offset inside bucket c
        seg[0] = sb[0 * DN_BLOCKS + b] - h_lds[b * MAXC + 0];
        seg[1] = tot0 + sb[1 * DN_BLOCKS + b] - h_lds[b * MAXC + 1];
        seg[2] = tot0 + tot1 + sb[2 * DN_BLOCKS + b] - h_lds[b * MAXC + 2];
        seg[3] = tot0 + tot1 + tot2 + sb[3 * DN_BLOCKS + b] - h_lds[b * MAXC + 3];
        cur[0] = 0; cur[1] = 0; cur[2] = 0; cur[3] = 0;
    }

    int np = n_elem * n_elem;
    for (int i = t; i < np; i += DN_THR) pt[i] = pair_tab[i];
    {
        int nwords = (n_nodes + 15) >> 4;
        const uint4* eg4 = (const uint4*)elem_g;
        uint4* el4 = (uint4*)elem;
        for (int i = t; i < nwords; i += DN_THR) el4[i] = eg4[i];
    }
    __syncthreads();

    long long e0 = (((long long)b * n_edges) / DN_BLOCKS) & ~3LL;
    long long e1 = (b == DN_BLOCKS - 1) ? (long long)n_edges
                 : ((((long long)(b + 1) * n_edges) / DN_BLOCKS) & ~3LL);
    long long vend = e1 & ~3LL;

    for (long long p = e0 + (long long)t * 4; p + 4 <= vend; p += (long long)DN_THR * 4) {
        int4   s4 = *(const int4*)(ei + p);
        int4   r4 = *(const int4*)(ei + n_edges + p);
        float4 x4 = *(const float4*)(x + p);
        float4 p0 = pt[elem[s4.x] * n_elem + elem[r4.x]];
        float4 p1 = pt[elem[s4.y] * n_elem + elem[r4.y]];
        float4 p2 = pt[elem[s4.z] * n_elem + elem[r4.z]];
        float4 p3 = pt[elem[s4.w] * n_elem + elem[r4.w]];
        scatter_bal((unsigned)r4.x, x4.x, p0, cur, seg, packedB, lane);
        scatter_bal((unsigned)r4.y, x4.y, p1, cur, seg, packedB, lane);
        scatter_bal((unsigned)r4.z, x4.z, p2, cur, seg, packedB, lane);
        scatter_bal((unsigned)r4.w, x4.w, p3, cur, seg, packedB, lane);
    }
    for (long long e2 = vend + t; e2 < e1; e2 += DN_THR) {
        int rr = ei[n_edges + e2];
        float4 pp = pt[elem[ei[e2]] * n_elem + elem[rr]];
        scatter_bal((unsigned)rr, x[e2], pp, cur, seg, packedB, lane);
    }
}

// ---------------- dispatch 3: balanced contiguous-bucket scan -> staggered atomics ---
__global__ __launch_bounds__(SCAN_THR)
void zbl_scan_a(const unsigned* __restrict__ packedB,
                const unsigned* __restrict__ hist,
                float* __restrict__ out,
                int n_nodes) {
    __shared__ __align__(16) float acc[P2_CHUNK];
    __shared__ unsigned h_lds[DN_BLOCKS * MAXC];
    __shared__ unsigned sb[MAXC * DN_BLOCKS];
    __shared__ unsigned tot[MAXC];
    const int b = blockIdx.x, t = threadIdx.x;

    for (int i = t; i < DN_BLOCKS * MAXC; i += SCAN_THR) h_lds[i] = hist[i];
    for (int i = t * 4; i < P2_CHUNK; i += SCAN_THR * 4)
        *(float4*)&acc[i] = make_float4(0.f, 0.f, 0.f, 0.f);
    __syncthreads();
    PREFIX_HIST(sb, h_lds, t);
    {
        const int c_ = t >> 8, bb_ = t & 255;
        if (bb_ == 255) tot[c_] = sb[t];
    }
    __syncthreads();

    int nb0, nb1, nb2, nb3, st1, st2, st3;
    long long g0, g1, g2, g3;
    scan_alloc(tot, nb0, nb1, nb2, nb3, st1, st2, st3, g0, g1, g2, g3);

    const int c   = (b >= st1) + (b >= st2) + (b >= st3);
    const int jb  = b - ((c == 0) ? 0 : (c == 1) ? st1 : (c == 2) ? st2 : st3);
    long long Tc  = (c == 0) ? g0 : (c == 1) ? g1 : (c == 2) ? g2 : g3;
    int nbc       = (c == 0) ? nb0 : (c == 1) ? nb1 : (c == 2) ? nb2 : nb3;
    long long csc = (c == 0) ? 0LL : (c == 1) ? g0 : (c == 2) ? g0 + g1 : g0 + g1 + g2;
    long long s = csc + Tc * jb / nbc;           // contiguous range [s, e)
    long long e = csc + Tc * (jb + 1) / nbc;

    if (s < e) {
        long long va = (s + 3) & ~3LL; if (va > e) va = e;
        long long ve = e & ~3LL;       if (ve < va) ve = va;
        for (long long i2 = s + t; i2 < va; i2 += SCAN_THR) {
            unsigned wd = packedB[i2]; ACC1(wd);
        }
        // 4-deep quarter strips over the contiguous interior (~19-27K words =>
        // sq ~ 4.7-6.7K > 4096, all 1024 threads active).
        long long m  = ve - va;
        long long sq = (m >> 4) << 2;
        const unsigned* p0 = packedB + va;
        for (long long o = (long long)t * 4; o < sq; o += (long long)SCAN_THR * 4) {
            uint4 qa = *(const uint4*)(p0 + o);
            uint4 qb = *(const uint4*)(p0 + sq + o);
            uint4 qc = *(const uint4*)(p0 + 2 * sq + o);
            uint4 qd = *(const uint4*)(p0 + 3 * sq + o);
            ACC4(qa); ACC4(qb); ACC4(qc); ACC4(qd);
        }
        for (long long i2 = va + 4 * sq + (long long)t * 4; i2 + 4 <= ve;
             i2 += (long long)SCAN_THR * 4) {
            uint4 q = *(const uint4*)(packedB + i2);
            ACC4(q);
        }
        for (long long i2 = ve + t; i2 < e; i2 += SCAN_THR) {
            unsigned wd = packedB[i2]; ACC1(wd);
        }
    }

    __syncthreads();
    // ---- flush: STAGGERED skip-zero global atomics (r5's lockstep sweep was the
    // regression: ~85 blocks/chunk hitting the same 64B lines simultaneously.
    // Rotating each block's start ~390 nodes apart decorrelates the line traffic).
    {
        long long nodebase = (long long)c << P2_SHIFT;
        int start = (b * 388) & (P2_CHUNK - 1) & ~3;
        for (int k = 0; k < P2_CHUNK; k += SCAN_THR * 4) {
            int i = (start + k + t * 4) & (P2_CHUNK - 1);
            float4 v = *(const float4*)&acc[i];
            long long n4 = nodebase + i;
            if (n4 + 3 < n_nodes) {
                if (v.x != 0.f) atomicAdd(&out[n4 + 0], v.x);
                if (v.y != 0.f) atomicAdd(&out[n4 + 1], v.y);
                if (v.z != 0.f) atomicAdd(&out[n4 + 2], v.z);
                if (v.w != 0.f) atomicAdd(&out[n4 + 3], v.w);
            } else {
                if (v.x != 0.f && n4 + 0 < n_nodes) atomicAdd(&out[n4 + 0], v.x);
                if (v.y != 0.f && n4 + 1 < n_nodes) atomicAdd(&out[n4 + 1], v.y);
                if (v.z != 0.f && n4 + 2 < n_nodes) atomicAdd(&out[n4 + 2], v.z);
                if (v.w != 0.f && n4 + 3 < n_nodes) atomicAdd(&out[n4 + 3], v.w);
            }
        }
    }
}

// ================= fallback path: node float4 table + direct device atomics =================
__global__ void zbl_node_prep(const float* __restrict__ node_attrs,
                              const int* __restrict__ atomic_numbers,
                              const float* __restrict__ covalent_radii,
                              float4* __restrict__ node_data,
                              float* __restrict__ out_zero,
                              int n_nodes, int n_elem) {
    int n = blockIdx.x * blockDim.x + threadIdx.x;
    if (n >= n_nodes) return;
    const float* row = node_attrs + (size_t)n * n_elem;
    float best = row[0];
    int bi = 0;
    for (int i = 1; i < n_elem; ++i) {
        float v = row[i];
        if (v > best) { best = v; bi = i; }
    }
    int Z = atomic_numbers[bi];
    float zf = (float)Z;
    node_data[n] = make_float4(zf, __powf(zf, 0.3f), covalent_radii[Z], 0.0f);
    out_zero[n] = 0.0f;
}

__global__ void zbl_edge_atomic(const float* __restrict__ x,
                                const int* __restrict__ edge_index,
                                const float4* __restrict__ node_data,
                                float* __restrict__ out,
                                int n_edges) {
    int e = blockIdx.x * blockDim.x + threadIdx.x;
    if (e >= n_edges) return;
    int snd = edge_index[e];
    int r = edge_index[n_edges + e];
    float xv = x[e];
    float4 du = node_data[snd];
    float4 dv = node_data[r];
    float rmax = du.z + dv.z;
    if (xv >= rmax) return;
    const float inv_a_pref = 1.0f / (0.4543f * 0.529f);
    float t = xv * (du.y + dv.y) * inv_a_pref;
    float phi = 0.1818f  * __expf(-3.2f    * t)
              + 0.5099f  * __expf(-0.9423f * t)
              + 0.2802f  * __expf(-0.4028f * t)
              + 0.02817f * __expf(-0.2016f * t);
    float v = KE_CONST * du.x * dv.x * phi / xv;
    float rr = xv / rmax;
    float r2 = rr * rr;
    float r6 = r2 * r2 * r2;
    float env = 1.0f - 28.0f * r6 + 48.0f * r6 * rr - 21.0f * r6 * r2;
    atomicAdd(&out[r], 0.5f * v * env);
}

extern "C" void kernel_launch(void* const* d_in, const int* in_sizes, int n_in,
                              void* d_out, int out_size, void* d_ws, size_t ws_size,
                              hipStream_t stream) {
    const float* x              = (const float*)d_in[0];
    const float* node_attrs     = (const float*)d_in[1];
    const int*   edge_index     = (const int*)d_in[2];
    const int*   atomic_numbers = (const int*)d_in[3];
    const float* covalent_radii = (const float*)d_in[4];
    float* out = (float*)d_out;

    int n_edges = in_sizes[0];
    int n_elem  = in_sizes[3];
    int n_nodes = in_sizes[1] / n_elem;

    int C = (n_nodes + P2_CHUNK - 1) >> P2_SHIFT;
    size_t elem_bytes   = (((size_t)n_nodes) + 255) & ~(size_t)255;
    size_t pair_bytes   = ((size_t)MAXE * MAXE * sizeof(float4) + 255) & ~(size_t)255;
    size_t hist_bytes   = (((size_t)DN_BLOCKS * MAXC * 4 + 64) + 255) & ~(size_t)255;
    size_t packed_bytes = (((size_t)n_edges * sizeof(unsigned)) + 255) & ~(size_t)255;
    bool fast = (C >= 1) && (C <= MAXC) && (n_nodes <= ELEM_CAP) &&
                (n_elem >= 1) && (n_elem <= MAXE) &&
                (ws_size >= elem_bytes + pair_bytes + hist_bytes + packed_bytes);

    if (fast) {
        unsigned char* elem     = (unsigned char*)d_ws;
        float4*        pair_tab = (float4*)((char*)d_ws + elem_bytes);
        unsigned*      hist     = (unsigned*)((char*)d_ws + elem_bytes + pair_bytes);
        unsigned*      packedB  = (unsigned*)((char*)d_ws + elem_bytes + pair_bytes + hist_bytes);

        zbl_prep<<<CNT_B + EB + 1, 1024, 0, stream>>>(
            node_attrs, edge_index, atomic_numbers, covalent_radii,
            elem, pair_tab, hist, out, n_edges, n_elem, n_nodes);

        zbl_dense<<<DN_BLOCKS, DN_THR, 0, stream>>>(
            x, edge_index, elem, pair_tab, hist, packedB,
            n_edges, n_elem, n_nodes);

        zbl_scan_a<<<SCAN_B, SCAN_THR, 0, stream>>>(
            packedB, hist, out, n_nodes);
        return;
    }

    // fallback: node table + plain device atomics
    float4* node_data = (float4*)d_ws;
    zbl_node_prep<<<(n_nodes + 255) / 256, 256, 0, stream>>>(
        node_attrs, atomic_numbers, covalent_radii, node_data,
        out, n_nodes, n_elem);
    zbl_edge_atomic<<<(n_edges + 255) / 256, 256, 0, stream>>>(
        x, edge_index, node_data, out, n_edges);
}

// Round 9
// 175.827 us; speedup vs baseline: 1.4146x; 1.4146x over previous
//
#include <hip/hip_runtime.h>

#define KE_CONST 14.3996454784255f

#define P2_SHIFT 15
#define P2_CHUNK 32768            // 128 KB LDS accumulator per chunk (scan phase)
#define MAXC     4
#define MAXE     16               // pair table up to 256 entries (4 KB LDS)
#define ELEM4_CAP 65536           // nibble-packed elem table cap (131072 nodes, 64 KB)
#define DN_THR   1024
#define DN_BLOCKS 256
#define SCAN_THR 1024
#define SCAN_B   256              // balanced scan blocks (1/CU)
#define CNT_B    256              // count blocks in prep (MUST match DN_BLOCKS slicing)
#define EB       32               // elem-argmax blocks in prep

// ---------------- deterministic proportional block allocation for the scan ----------
__device__ __forceinline__ void scan_alloc(const unsigned* __restrict__ g_,
        int& nb0, int& nb1, int& nb2, int& nb3,
        int& st1, int& st2, int& st3,
        long long& g0, long long& g1, long long& g2, long long& g3) {
    g0 = g_[0]; g1 = g_[1]; g2 = g_[2]; g3 = g_[3];
    long long tot = g0 + g1 + g2 + g3; if (tot < 1) tot = 1;
    nb0 = (int)((g0 * SCAN_B) / tot); if (nb0 < 1) nb0 = 1;
    nb1 = (int)((g1 * SCAN_B) / tot); if (nb1 < 1) nb1 = 1;
    nb2 = (int)((g2 * SCAN_B) / tot); if (nb2 < 1) nb2 = 1;
    nb3 = (int)((g3 * SCAN_B) / tot); if (nb3 < 1) nb3 = 1;
    int sum = nb0 + nb1 + nb2 + nb3;
    while (sum > SCAN_B) {
        if      (nb0 >= nb1 && nb0 >= nb2 && nb0 >= nb3) nb0--;
        else if (nb1 >= nb2 && nb1 >= nb3)               nb1--;
        else if (nb2 >= nb3)                             nb2--;
        else                                             nb3--;
        sum--;
    }
    while (sum < SCAN_B) {
        if      (nb0 >= nb1 && nb0 >= nb2 && nb0 >= nb3) nb0++;
        else if (nb1 >= nb2 && nb1 >= nb3)               nb1++;
        else if (nb2 >= nb3)                             nb2++;
        else                                             nb3++;
        sum++;
    }
    st1 = nb0; st2 = nb0 + nb1; st3 = nb0 + nb1 + nb2;
}

// ---------------- per-edge bf16 value from pair-table entry ----------------
__device__ __forceinline__ unsigned enc_val16(float xv, const float4& p) {
    float t = xv * p.x;
    float phi = 0.1818f  * __expf(-3.2f    * t)
              + 0.5099f  * __expf(-0.9423f * t)
              + 0.2802f  * __expf(-0.4028f * t)
              + 0.02817f * __expf(-0.2016f * t);
    float rr = xv * p.w;
    float r2 = rr * rr;
    float r6 = r2 * r2 * r2;
    float env = 1.0f - 28.0f * r6 + 48.0f * r6 * rr - 21.0f * r6 * r2;
    float val = fmaxf(p.y * phi / xv * env, 0.0f);     // clamp r->1 cancellation negatives
    unsigned e = (__float_as_uint(val) + 0x8000u) >> 16;   // round-to-nearest bf16
    return (xv < p.z) ? e : 0u;
}

// ---------------- wave-aggregated bucketed scatter (<=4 LDS atomics / wave-round) ----
__device__ __forceinline__ void scatter_bal(unsigned rw, float xv, const float4& p,
                                            unsigned* cur, const unsigned* seg,
                                            unsigned* __restrict__ packedB, int lane) {
    unsigned cc = rw >> P2_SHIFT;
    unsigned w  = ((rw & (P2_CHUNK - 1)) << 16) | enc_val16(xv, p);
    unsigned long long m0 = __ballot(cc == 0), m1 = __ballot(cc == 1),
                       m2 = __ballot(cc == 2), m3 = __ballot(cc == 3);
    unsigned long long mine = (cc == 0) ? m0 : (cc == 1) ? m1 : (cc == 2) ? m2 : m3;
    int ldr = __ffsll((long long)mine) - 1;
    unsigned base = 0;
    if (lane == ldr) base = atomicAdd(&cur[cc], (unsigned)__popcll(mine));
    base = __shfl(base, ldr, 64);
    unsigned pos = base + (unsigned)__popcll(mine & ((1ull << lane) - 1ull));
    packedB[(size_t)seg[cc] + pos] = w;
}

// zero-mask: ~30% of words encode bf16 0 (env cutoff) — skip the DS RMW entirely.
#define ACC1(W) { if ((W) & 0xFFFFu) \
    atomicAdd(&acc[(W) >> 16], __uint_as_float(((W) & 0xFFFFu) << 16)); }
#define ACC4(Q) { ACC1((Q).x); ACC1((Q).y); ACC1((Q).z); ACC1((Q).w); }

// ---------------- in-LDS per-chunk inclusive prefix over 256 block histograms -------
// (dense only; scan needs just the 4 totals and computes them by butterfly)
#define PREFIX_HIST(sb, h_lds, t)                                              \
    {                                                                          \
        const int c_ = (t) >> 8, bb_ = (t) & 255;                              \
        (sb)[t] = (h_lds)[bb_ * MAXC + c_];                                    \
        __syncthreads();                                                       \
        for (int off_ = 1; off_ < DN_BLOCKS; off_ <<= 1) {                     \
            unsigned add_ = (bb_ >= off_) ? (sb)[c_ * DN_BLOCKS + bb_ - off_]  \
                                          : 0u;                                \
            __syncthreads();                                                   \
            (sb)[t] += add_;                                                   \
            __syncthreads();                                                   \
        }                                                                      \
    }

// ---------------- dispatch 1: count hist (0..255), argmax->nibbles, pairs -----------
__global__ __launch_bounds__(1024)
void zbl_prep(const float* __restrict__ node_attrs,
              const int* __restrict__ ei,
              const int* __restrict__ atomic_numbers,
              const float* __restrict__ covalent_radii,
              unsigned char* __restrict__ elem4_g,
              float4* __restrict__ pair_tab,
              unsigned* __restrict__ hist,
              int n_edges, int n_elem, int n_nodes) {
    const int b = blockIdx.x, t = threadIdx.x, lane = t & 63;

    if (b < CNT_B) {
        __shared__ unsigned h[MAXC];
        if (t < MAXC) h[t] = 0u;
        __syncthreads();
        long long e0 = (((long long)b * n_edges) / CNT_B) & ~3LL;
        long long e1 = (b == CNT_B - 1) ? (long long)n_edges
                     : ((((long long)(b + 1) * n_edges) / CNT_B) & ~3LL);
        const int* r = ei + n_edges;
        unsigned c0 = 0, c1 = 0, c2 = 0, c3 = 0;
        long long vend = e1 & ~3LL;
        for (long long p = e0 + (long long)t * 4; p + 4 <= vend; p += 1024LL * 4) {
            int4 a = *(const int4*)(r + p);
            unsigned cc;
            cc = ((unsigned)a.x) >> P2_SHIFT; c0 += (cc==0); c1 += (cc==1); c2 += (cc==2); c3 += (cc==3);
            cc = ((unsigned)a.y) >> P2_SHIFT; c0 += (cc==0); c1 += (cc==1); c2 += (cc==2); c3 += (cc==3);
            cc = ((unsigned)a.z) >> P2_SHIFT; c0 += (cc==0); c1 += (cc==1); c2 += (cc==2); c3 += (cc==3);
            cc = ((unsigned)a.w) >> P2_SHIFT; c0 += (cc==0); c1 += (cc==1); c2 += (cc==2); c3 += (cc==3);
        }
        for (long long e2 = vend + t; e2 < e1; e2 += 1024) {
            unsigned cc = ((unsigned)r[e2]) >> P2_SHIFT;
            c0 += (cc==0); c1 += (cc==1); c2 += (cc==2); c3 += (cc==3);
        }
        for (int o = 32; o; o >>= 1) {
            c0 += __shfl_down(c0, o, 64); c1 += __shfl_down(c1, o, 64);
            c2 += __shfl_down(c2, o, 64); c3 += __shfl_down(c3, o, 64);
        }
        if (lane == 0) {
            atomicAdd(&h[0], c0); atomicAdd(&h[1], c1);
            atomicAdd(&h[2], c2); atomicAdd(&h[3], c3);
        }
        __syncthreads();
        if (t < MAXC) hist[b * MAXC + t] = h[t];   // plain store — no gcount, no memset
    } else if (b < CNT_B + EB) {
        // ---- per-node element id, nibble-packed: thread handles a node PAIR ----
        int bb = b - CNT_B;
        int npairs = (n_nodes + 1) >> 1;
        int p0 = (int)(((long long)bb * npairs) / EB);
        int p1 = (int)(((long long)(bb + 1) * npairs) / EB);
        for (int p = p0 + t; p < p1; p += 1024) {
            int n0 = 2 * p, n1 = 2 * p + 1;
            const float* row = node_attrs + (size_t)n0 * n_elem;
            float best = row[0]; int bi = 0;
            for (int i = 1; i < n_elem; ++i) {
                float v = row[i];
                if (v > best) { best = v; bi = i; }
            }
            unsigned byte = (unsigned)bi;
            if (n1 < n_nodes) {
                const float* row2 = node_attrs + (size_t)n1 * n_elem;
                float b2 = row2[0]; int bj = 0;
                for (int i = 1; i < n_elem; ++i) {
                    float v = row2[i];
                    if (v > b2) { b2 = v; bj = i; }
                }
                byte |= ((unsigned)bj) << 4;
            }
            elem4_g[p] = (unsigned char)byte;
        }
    } else {
        int np = n_elem * n_elem;
        if (t < np) {
            int eu = t / n_elem, ev = t - eu * n_elem;
            int Zu = atomic_numbers[eu], Zv = atomic_numbers[ev];
            float zu = (float)Zu, zv = (float)Zv;
            float inv_a = (__powf(zu, 0.3f) + __powf(zv, 0.3f)) * (1.0f / (0.4543f * 0.529f));
            float rmax  = covalent_radii[Zu] + covalent_radii[Zv];
            pair_tab[t] = make_float4(inv_a, 0.5f * KE_CONST * zu * zv, rmax, 1.0f / rmax);
        }
    }
}

// ---------------- dispatch 2: prefix-from-hist + dense compute + bucket scatter -----
// Nibble elem table: LDS = 64K(elem4) + 4K(pt) + 4K(h_lds) + 4K(sb) ~ 76 KB
// -> 2 blocks/CU (r7's 137 KB byte table forced 1/CU; dense was latency-bound).
__global__ __launch_bounds__(DN_THR)
void zbl_dense(const float* __restrict__ x,
               const int* __restrict__ ei,
               const unsigned char* __restrict__ elem4_g,
               const float4* __restrict__ pair_tab,
               const unsigned* __restrict__ hist,
               unsigned* __restrict__ packedB,
               int n_edges, int n_elem, int n_nodes) {
    __shared__ __align__(16) unsigned char elem4[ELEM4_CAP];
    __shared__ float4 pt[MAXE * MAXE];
    __shared__ unsigned h_lds[DN_BLOCKS * MAXC];
    __shared__ unsigned sb[MAXC * DN_BLOCKS];
    __shared__ unsigned cur[MAXC], seg[MAXC];

    const int b = blockIdx.x, t = threadIdx.x, lane = t & 63;

    for (int i = t; i < DN_BLOCKS * MAXC; i += DN_THR) h_lds[i] = hist[i];
    __syncthreads();
    PREFIX_HIST(sb, h_lds, t);

    if (t == 0) {
        unsigned tot0 = sb[0 * DN_BLOCKS + 255];
        unsigned tot1 = sb[1 * DN_BLOCKS + 255];
        unsigned tot2 = sb[2 * DN_BLOCKS + 255];
        // global base of bucket c + this block's exclusive offset inside bucket c
        seg[0] = sb[0 * DN_BLOCKS + b] - h_lds[b * MAXC + 0];
        seg[1] = tot0 + sb[1 * DN_BLOCKS + b] - h_lds[b * MAXC + 1];
        seg[2] = tot0 + tot1 + sb[2 * DN_BLOCKS + b] - h_lds[b * MAXC + 2];
        seg[3] = tot0 + tot1 + tot2 + sb[3 * DN_BLOCKS + b] - h_lds[b * MAXC + 3];
        cur[0] = 0; cur[1] = 0; cur[2] = 0; cur[3] = 0;
    }

    int np = n_elem * n_elem;
    for (int i = t; i < np; i += DN_THR) pt[i] = pair_tab[i];
    {
        int nbytes = (n_nodes + 1) >> 1;
        int nwords = (nbytes + 15) >> 4;
        const uint4* eg4 = (const uint4*)elem4_g;
        uint4* el4 = (uint4*)elem4;
        for (int i = t; i < nwords; i += DN_THR) el4[i] = eg4[i];
    }
    __syncthreads();

    long long e0 = (((long long)b * n_edges) / DN_BLOCKS) & ~3LL;
    long long e1 = (b == DN_BLOCKS - 1) ? (long long)n_edges
                 : ((((long long)(b + 1) * n_edges) / DN_BLOCKS) & ~3LL);
    long long vend = e1 & ~3LL;

    #define EG(n) ((unsigned)((elem4[(unsigned)(n) >> 1] >> (((unsigned)(n) & 1u) << 2)) & 15u))

    for (long long p = e0 + (long long)t * 4; p + 4 <= vend; p += (long long)DN_THR * 4) {
        int4   s4 = *(const int4*)(ei + p);
        int4   r4 = *(const int4*)(ei + n_edges + p);
        float4 x4 = *(const float4*)(x + p);
        float4 p0 = pt[EG(s4.x) * n_elem + EG(r4.x)];
        float4 p1 = pt[EG(s4.y) * n_elem + EG(r4.y)];
        float4 p2 = pt[EG(s4.z) * n_elem + EG(r4.z)];
        float4 p3 = pt[EG(s4.w) * n_elem + EG(r4.w)];
        scatter_bal((unsigned)r4.x, x4.x, p0, cur, seg, packedB, lane);
        scatter_bal((unsigned)r4.y, x4.y, p1, cur, seg, packedB, lane);
        scatter_bal((unsigned)r4.z, x4.z, p2, cur, seg, packedB, lane);
        scatter_bal((unsigned)r4.w, x4.w, p3, cur, seg, packedB, lane);
    }
    for (long long e2 = vend + t; e2 < e1; e2 += DN_THR) {
        int rr = ei[n_edges + e2];
        float4 pp = pt[EG(ei[e2]) * n_elem + EG(rr)];
        scatter_bal((unsigned)rr, x[e2], pp, cur, seg, packedB, lane);
    }
    #undef EG
}

// ---------------- dispatch 3: balanced contiguous-bucket scan, 4-deep strips --------
__global__ __launch_bounds__(SCAN_THR)
void zbl_scan_t(const unsigned* __restrict__ packedB,
                const unsigned* __restrict__ hist,
                float* __restrict__ partial,
                unsigned* __restrict__ tot_ws) {
    __shared__ __align__(16) float acc[P2_CHUNK];
    __shared__ unsigned tot[MAXC];
    const int b = blockIdx.x, t = threadIdx.x;

    if (t < MAXC) tot[t] = 0u;
    for (int i = t * 4; i < P2_CHUNK; i += SCAN_THR * 4)
        *(float4*)&acc[i] = make_float4(0.f, 0.f, 0.f, 0.f);
    __syncthreads();

    // ---- bucket totals: one coalesced read of the 1024-entry hist + xor-butterfly
    // over lanes with the same (lane&3) -> 4 sums per wave, 64 tiny LDS atomics.
    {
        unsigned v = hist[t];                 // t in [0,1024) == CNT_B*MAXC exactly
        int lane = t & 63;
        v += __shfl_xor(v, 4, 64);
        v += __shfl_xor(v, 8, 64);
        v += __shfl_xor(v, 16, 64);
        v += __shfl_xor(v, 32, 64);
        if (lane < MAXC) atomicAdd(&tot[lane], v);
    }
    __syncthreads();
    if (b == 0 && t < MAXC) tot_ws[t] = tot[t];    // geometry for the reduce kernel

    int nb0, nb1, nb2, nb3, st1, st2, st3;
    long long g0, g1, g2, g3;
    scan_alloc(tot, nb0, nb1, nb2, nb3, st1, st2, st3, g0, g1, g2, g3);

    const int c   = (b >= st1) + (b >= st2) + (b >= st3);
    const int jb  = b - ((c == 0) ? 0 : (c == 1) ? st1 : (c == 2) ? st2 : st3);
    long long Tc  = (c == 0) ? g0 : (c == 1) ? g1 : (c == 2) ? g2 : g3;
    int nbc       = (c == 0) ? nb0 : (c == 1) ? nb1 : (c == 2) ? nb2 : nb3;
    long long csc = (c == 0) ? 0LL : (c == 1) ? g0 : (c == 2) ? g0 + g1 : g0 + g1 + g2;
    long long s = csc + Tc * jb / nbc;           // contiguous range [s, e)
    long long e = csc + Tc * (jb + 1) / nbc;

    if (s < e) {
        long long va = (s + 3) & ~3LL; if (va > e) va = e;
        long long ve = e & ~3LL;       if (ve < va) ve = va;
        for (long long i2 = s + t; i2 < va; i2 += SCAN_THR) {
            unsigned wd = packedB[i2]; ACC1(wd);
        }
        // 4-deep quarter strips over the contiguous interior (~19-27K words =>
        // sq ~ 4.7-6.7K > 4096, all 1024 threads active).
        long long m  = ve - va;
        long long sq = (m >> 4) << 2;
        const unsigned* p0 = packedB + va;
        for (long long o = (long long)t * 4; o < sq; o += (long long)SCAN_THR * 4) {
            uint4 qa = *(const uint4*)(p0 + o);
            uint4 qb = *(const uint4*)(p0 + sq + o);
            uint4 qc = *(const uint4*)(p0 + 2 * sq + o);
            uint4 qd = *(const uint4*)(p0 + 3 * sq + o);
            ACC4(qa); ACC4(qb); ACC4(qc); ACC4(qd);
        }
        for (long long i2 = va + 4 * sq + (long long)t * 4; i2 + 4 <= ve;
             i2 += (long long)SCAN_THR * 4) {
            uint4 q = *(const uint4*)(packedB + i2);
            ACC4(q);
        }
        for (long long i2 = ve + t; i2 < e; i2 += SCAN_THR) {
            unsigned wd = packedB[i2]; ACC1(wd);
        }
    }

    __syncthreads();
    // coalesced partial store (global-atomics flush measured dead in r5/r8)
    float* pp = partial + (size_t)b * P2_CHUNK;
    for (int i = t * 4; i < P2_CHUNK; i += SCAN_THR * 4)
        *(float4*)(pp + i) = *(const float4*)&acc[i];
}

// ---------------- dispatch 4: reduce per-chunk partials per node ----------------
__global__ void zbl_reduce_p(const float* __restrict__ partial,
                             const unsigned* __restrict__ tot_ws,
                             float* __restrict__ out,
                             int n_nodes) {
    int i = blockIdx.x * blockDim.x + threadIdx.x;
    if (i >= n_nodes) return;

    unsigned tt[MAXC] = { tot_ws[0], tot_ws[1], tot_ws[2], tot_ws[3] };
    int nb0, nb1, nb2, nb3, st1, st2, st3;
    long long g0, g1, g2, g3;
    scan_alloc(tt, nb0, nb1, nb2, nb3, st1, st2, st3, g0, g1, g2, g3);

    int c  = i >> P2_SHIFT;
    int li = i & (P2_CHUNK - 1);
    int st  = (c == 0) ? 0 : (c == 1) ? st1 : (c == 2) ? st2 : st3;
    int nbc = (c == 0) ? nb0 : (c == 1) ? nb1 : (c == 2) ? nb2 : nb3;
    const float* p = partial + (size_t)st * P2_CHUNK + li;
    float s0 = 0.f, s1 = 0.f, s2 = 0.f, s3 = 0.f;
    int j = 0;
    for (; j + 4 <= nbc; j += 4) {
        s0 += p[(size_t)(j + 0) * P2_CHUNK];
        s1 += p[(size_t)(j + 1) * P2_CHUNK];
        s2 += p[(size_t)(j + 2) * P2_CHUNK];
        s3 += p[(size_t)(j + 3) * P2_CHUNK];
    }
    for (; j < nbc; ++j) s0 += p[(size_t)j * P2_CHUNK];
    out[i] = (s0 + s1) + (s2 + s3);
}

// ================= fallback path: node float4 table + direct device atomics =================
__global__ void zbl_node_prep(const float* __restrict__ node_attrs,
                              const int* __restrict__ atomic_numbers,
                              const float* __restrict__ covalent_radii,
                              float4* __restrict__ node_data,
                              float* __restrict__ out_zero,
                              int n_nodes, int n_elem) {
    int n = blockIdx.x * blockDim.x + threadIdx.x;
    if (n >= n_nodes) return;
    const float* row = node_attrs + (size_t)n * n_elem;
    float best = row[0];
    int bi = 0;
    for (int i = 1; i < n_elem; ++i) {
        float v = row[i];
        if (v > best) { best = v; bi = i; }
    }
    int Z = atomic_numbers[bi];
    float zf = (float)Z;
    node_data[n] = make_float4(zf, __powf(zf, 0.3f), covalent_radii[Z], 0.0f);
    out_zero[n] = 0.0f;
}

__global__ void zbl_edge_atomic(const float* __restrict__ x,
                                const int* __restrict__ edge_index,
                                const float4* __restrict__ node_data,
                                float* __restrict__ out,
                                int n_edges) {
    int e = blockIdx.x * blockDim.x + threadIdx.x;
    if (e >= n_edges) return;
    int snd = edge_index[e];
    int r = edge_index[n_edges + e];
    float xv = x[e];
    float4 du = node_data[snd];
    float4 dv = node_data[r];
    float rmax = du.z + dv.z;
    if (xv >= rmax) return;
    const float inv_a_pref = 1.0f / (0.4543f * 0.529f);
    float t = xv * (du.y + dv.y) * inv_a_pref;
    float phi = 0.1818f  * __expf(-3.2f    * t)
              + 0.5099f  * __expf(-0.9423f * t)
              + 0.2802f  * __expf(-0.4028f * t)
              + 0.02817f * __expf(-0.2016f * t);
    float v = KE_CONST * du.x * dv.x * phi / xv;
    float rr = xv / rmax;
    float r2 = rr * rr;
    float r6 = r2 * r2 * r2;
    float env = 1.0f - 28.0f * r6 + 48.0f * r6 * rr - 21.0f * r6 * r2;
    atomicAdd(&out[r], 0.5f * v * env);
}

extern "C" void kernel_launch(void* const* d_in, const int* in_sizes, int n_in,
                              void* d_out, int out_size, void* d_ws, size_t ws_size,
                              hipStream_t stream) {
    const float* x              = (const float*)d_in[0];
    const float* node_attrs     = (const float*)d_in[1];
    const int*   edge_index     = (const int*)d_in[2];
    const int*   atomic_numbers = (const int*)d_in[3];
    const float* covalent_radii = (const float*)d_in[4];
    float* out = (float*)d_out;

    int n_edges = in_sizes[0];
    int n_elem  = in_sizes[3];
    int n_nodes = in_sizes[1] / n_elem;

    int C = (n_nodes + P2_CHUNK - 1) >> P2_SHIFT;
    size_t elem_bytes   = ((((size_t)n_nodes + 1) >> 1) + 255) & ~(size_t)255;
    size_t pair_bytes   = ((size_t)MAXE * MAXE * sizeof(float4) + 255) & ~(size_t)255;
    size_t hist_bytes   = (((size_t)DN_BLOCKS * MAXC * 4 + 64) + 255) & ~(size_t)255;
    size_t packed_bytes = (((size_t)n_edges * sizeof(unsigned)) + 255) & ~(size_t)255;
    size_t part_bytes   = (size_t)SCAN_B * P2_CHUNK * sizeof(float);
    bool fast = (C >= 1) && (C <= MAXC) && (n_nodes <= 2 * ELEM4_CAP) &&
                (n_elem >= 1) && (n_elem <= MAXE) &&
                (ws_size >= elem_bytes + pair_bytes + hist_bytes + packed_bytes + part_bytes);

    if (fast) {
        unsigned char* elem4    = (unsigned char*)d_ws;
        float4*        pair_tab = (float4*)((char*)d_ws + elem_bytes);
        unsigned*      hist     = (unsigned*)((char*)d_ws + elem_bytes + pair_bytes);
        unsigned*      tot_ws   = hist + DN_BLOCKS * MAXC;
        unsigned*      packedB  = (unsigned*)((char*)d_ws + elem_bytes + pair_bytes + hist_bytes);
        float*         part     = (float*)((char*)d_ws + elem_bytes + pair_bytes + hist_bytes + packed_bytes);

        zbl_prep<<<CNT_B + EB + 1, 1024, 0, stream>>>(
            node_attrs, edge_index, atomic_numbers, covalent_radii,
            elem4, pair_tab, hist, n_edges, n_elem, n_nodes);

        zbl_dense<<<DN_BLOCKS, DN_THR, 0, stream>>>(
            x, edge_index, elem4, pair_tab, hist, packedB,
            n_edges, n_elem, n_nodes);

        zbl_scan_t<<<SCAN_B, SCAN_THR, 0, stream>>>(
            packedB, hist, part, tot_ws);

        zbl_reduce_p<<<(n_nodes + 255) / 256, 256, 0, stream>>>(
            part, tot_ws, out, n_nodes);
        return;
    }

    // fallback: node table + plain device atomics
    float4* node_data = (float4*)d_ws;
    zbl_node_prep<<<(n_nodes + 255) / 256, 256, 0, stream>>>(
        node_attrs, atomic_numbers, covalent_radii, node_data,
        out, n_nodes, n_elem);
    zbl_edge_atomic<<<(n_edges + 255) / 256, 256, 0, stream>>>(
        x, edge_index, node_data, out, n_edges);
}